// Round 1
// baseline (141.785 us; speedup 1.0000x reference)
//
#include <hip/hip_runtime.h>

constexpr int B = 2, C = 21, H = 256, W = 256;
constexpr int HW = H * W;
constexpr int K = 5, K2 = 25;
constexpr int TW = 32, TH = 8;      // pixel tile per 256-thread block
constexpr int LH = TH + 4, LW = TW + 4;

// ---------------------------------------------------------------------------
// Kernel 1: bilateral weights w[b][k][y][x] = spatial_w[k] * color_w(b,k,y,x)
// OOB taps don't matter (q is zero there), but we mirror zero-padded img.
// ---------------------------------------------------------------------------
__global__ __launch_bounds__(256) void compute_w_kernel(
        const float* __restrict__ img, float* __restrict__ w) {
    int idx = blockIdx.x * blockDim.x + threadIdx.x;
    if (idx >= B * HW) return;
    int b = idx / HW;
    int p = idx % HW;
    int y = p / W, x = p % W;
    const float* im = img + (size_t)b * 3 * HW;
    float c0 = im[0 * HW + p], c1 = im[1 * HW + p], c2 = im[2 * HW + p];

    // normalized spatial gaussian (sigma = 5.0): exp(-(dy^2+dx^2)/50)/S
    float sk[K2];
    float S = 0.f;
#pragma unroll
    for (int k = 0; k < K2; ++k) {
        int dy = k / K - 2, dx = k % K - 2;
        float v = __expf(-(float)(dy * dy + dx * dx) * (1.0f / 50.0f));
        sk[k] = v;
        S += v;
    }
    float invS = 1.0f / S;

#pragma unroll
    for (int k = 0; k < K2; ++k) {
        int dy = k / K - 2, dx = k % K - 2;
        int ny = y + dy, nx = x + dx;
        float d0 = -c0, d1 = -c1, d2 = -c2;   // zero-padded neighbor
        if (ny >= 0 && ny < H && nx >= 0 && nx < W) {
            int np = ny * W + nx;
            d0 += im[0 * HW + np];
            d1 += im[1 * HW + np];
            d2 += im[2 * HW + np];
        }
        // color sigma 0.1 -> 1/(2*sigma^2) = 50
        float cw = __expf(-(d0 * d0 + d1 * d1 + d2 * d2) * 50.0f);
        w[((size_t)b * K2 + k) * HW + p] = sk[k] * invS * cw;
    }
}

// ---------------------------------------------------------------------------
// Kernel 2: q0 = softmax(logits) over channel dim
// ---------------------------------------------------------------------------
__global__ __launch_bounds__(256) void softmax_init_kernel(
        const float* __restrict__ logits, float* __restrict__ q) {
    int idx = blockIdx.x * blockDim.x + threadIdx.x;
    if (idx >= B * HW) return;
    int b = idx / HW, p = idx % HW;
    const float* lg = logits + (size_t)b * C * HW + p;
    float z[C];
    float mx = -1e30f;
#pragma unroll
    for (int c = 0; c < C; ++c) {
        z[c] = lg[(size_t)c * HW];
        mx = fmaxf(mx, z[c]);
    }
    float s = 0.f;
#pragma unroll
    for (int c = 0; c < C; ++c) {
        z[c] = __expf(z[c] - mx);
        s += z[c];
    }
    float inv = 1.0f / s;
    float* qo = q + (size_t)b * C * HW + p;
#pragma unroll
    for (int c = 0; c < C; ++c) qo[(size_t)c * HW] = z[c] * inv;
}

// ---------------------------------------------------------------------------
// Kernel 3 (x5): one mean-field iteration, fully fused.
//   m_c   = q_c (spatial conv is ~delta: center weight == 1.0f in f32)
//         + sum_k w_k * q_unf[c,k]
//   z_i   = logits_i - sum_j compat[i][j] * m_j
//   q_out = softmax(z)
// ---------------------------------------------------------------------------
__global__ __launch_bounds__(256) void crf_iter_kernel(
        const float* __restrict__ qin, const float* __restrict__ w,
        const float* __restrict__ logits, const float* __restrict__ compat,
        float* __restrict__ qout) {
    __shared__ float sq[C][LH][LW];     // 21*12*36*4 = 36288 B
    __shared__ float scm[C * C];        // 1764 B

    int b = blockIdx.z;
    int x0 = blockIdx.x * TW, y0 = blockIdx.y * TH;
    int tid = threadIdx.x;

    for (int i = tid; i < C * C; i += 256) scm[i] = compat[i];

    const float* qb = qin + (size_t)b * C * HW;
    for (int i = tid; i < C * LH * LW; i += 256) {
        int c = i / (LH * LW);
        int r = i % (LH * LW);
        int ly = r / LW, lx = r % LW;
        int gy = y0 + ly - 2, gx = x0 + lx - 2;
        float v = 0.f;
        if (gy >= 0 && gy < H && gx >= 0 && gx < W)
            v = qb[(size_t)c * HW + gy * W + gx];
        sq[c][ly][lx] = v;
    }
    __syncthreads();

    int tx = tid % TW, ty = tid / TW;
    int x = x0 + tx, y = y0 + ty;
    int p = y * W + x;

    // per-pixel bilateral weights in registers (coalesced per k)
    float wk[K2];
#pragma unroll
    for (int k = 0; k < K2; ++k) wk[k] = w[((size_t)b * K2 + k) * HW + p];

    float m[C];
#pragma unroll
    for (int c = 0; c < C; ++c) {
        float acc = sq[c][ty + 2][tx + 2];   // spatial (delta) term
#pragma unroll
        for (int k = 0; k < K2; ++k)
            acc += wk[k] * sq[c][ty + k / K][tx + k % K];
        m[c] = acc;
    }

    const float* lg = logits + (size_t)b * C * HW + p;
    float z[C];
    float mx = -1e30f;
#pragma unroll
    for (int i = 0; i < C; ++i) {
        float pw = 0.f;
#pragma unroll
        for (int j = 0; j < C; ++j) pw += scm[i * C + j] * m[j];
        float zi = lg[(size_t)i * HW] - pw;
        z[i] = zi;
        mx = fmaxf(mx, zi);
    }
    float s = 0.f;
#pragma unroll
    for (int i = 0; i < C; ++i) {
        z[i] = __expf(z[i] - mx);
        s += z[i];
    }
    float inv = 1.0f / s;
    float* qo = qout + (size_t)b * C * HW + p;
#pragma unroll
    for (int i = 0; i < C; ++i) qo[(size_t)i * HW] = z[i] * inv;
}

// ---------------------------------------------------------------------------
extern "C" void kernel_launch(void* const* d_in, const int* in_sizes, int n_in,
                              void* d_out, int out_size, void* d_ws, size_t ws_size,
                              hipStream_t stream) {
    const float* logits = (const float*)d_in[0];
    const float* img    = (const float*)d_in[1];
    // d_in[2] = gt_edges (dead code in reference)
    const float* compat = (const float*)d_in[3];
    float* out = (float*)d_out;

    char* ws = (char*)d_ws;
    float* w  = (float*)ws;                                   // B*K2*HW floats
    float* qa = (float*)(ws + (size_t)B * K2 * HW * 4);       // B*C*HW floats
    float* qb = qa + (size_t)B * C * HW;                      // B*C*HW floats

    int npix = B * HW;
    int nb = (npix + 255) / 256;
    compute_w_kernel<<<nb, 256, 0, stream>>>(img, w);
    softmax_init_kernel<<<nb, 256, 0, stream>>>(logits, qa);

    dim3 grid(W / TW, H / TH, B);
    crf_iter_kernel<<<grid, 256, 0, stream>>>(qa, w, logits, compat, qb);
    crf_iter_kernel<<<grid, 256, 0, stream>>>(qb, w, logits, compat, qa);
    crf_iter_kernel<<<grid, 256, 0, stream>>>(qa, w, logits, compat, qb);
    crf_iter_kernel<<<grid, 256, 0, stream>>>(qb, w, logits, compat, qa);
    crf_iter_kernel<<<grid, 256, 0, stream>>>(qa, w, logits, compat, out);
}

// Round 2
// 114.092 us; speedup vs baseline: 1.2427x; 1.2427x over previous
//
#include <hip/hip_runtime.h>

constexpr int Bn = 2, C = 21, H = 256, W = 256, HW = H * W;
constexpr int K = 5, K2 = 25;
constexpr int TW = 32, TH = 8;            // 256 pixels per block
constexpr int LH = TH + 4, LW = TW + 4;
constexpr int CA = 11;                    // channels owned by half 0 (half 1: 10)

// ---------------------------------------------------------------------------
// Prep: bilateral weights w[b][k][p] AND q0 = softmax(logits), fused.
// ---------------------------------------------------------------------------
__global__ __launch_bounds__(256) void prep_kernel(
        const float* __restrict__ img, const float* __restrict__ logits,
        float* __restrict__ w, float* __restrict__ q) {
    int idx = blockIdx.x * 256 + threadIdx.x;
    if (idx >= Bn * HW) return;
    int b = idx / HW, p = idx % HW;
    int y = p / W, x = p % W;
    const float* im = img + (size_t)b * 3 * HW;
    float c0 = im[p], c1 = im[HW + p], c2 = im[2 * HW + p];

    // normalized spatial gaussian, sigma=5 -> exp(-(dy^2+dx^2)/50)
    float sk[K2], S = 0.f;
#pragma unroll
    for (int k = 0; k < K2; ++k) {
        int dy = k / K - 2, dx = k % K - 2;
        float v = __expf(-(float)(dy * dy + dx * dx) * 0.02f);
        sk[k] = v; S += v;
    }
    float invS = 1.f / S;
#pragma unroll
    for (int k = 0; k < K2; ++k) {
        int dy = k / K - 2, dx = k % K - 2;
        int ny = y + dy, nx = x + dx;
        float d0 = -c0, d1 = -c1, d2 = -c2;     // zero-padded neighbor
        if ((unsigned)ny < H && (unsigned)nx < W) {
            int np = ny * W + nx;
            d0 += im[np]; d1 += im[HW + np]; d2 += im[2 * HW + np];
        }
        float cw = __expf(-(d0 * d0 + d1 * d1 + d2 * d2) * 50.f);  // sigma_c=0.1
        w[((size_t)b * K2 + k) * HW + p] = sk[k] * invS * cw;
    }
    // q0 = softmax(logits)
    const float* lg = logits + (size_t)b * C * HW + p;
    float z[C], mx = -1e30f;
#pragma unroll
    for (int c = 0; c < C; ++c) { z[c] = lg[(size_t)c * HW]; mx = fmaxf(mx, z[c]); }
    float s = 0.f;
#pragma unroll
    for (int c = 0; c < C; ++c) { z[c] = __expf(z[c] - mx); s += z[c]; }
    float inv = 1.f / s;
    float* qo = q + (size_t)b * C * HW + p;
#pragma unroll
    for (int c = 0; c < C; ++c) qo[(size_t)c * HW] = z[c] * inv;
}

// ---------------------------------------------------------------------------
// One mean-field iteration. 512 threads = 2 threads per pixel (channel split:
// lanes 0-31 of each wave own c[0..10], lanes 32-63 own c[11..20] of the SAME
// 32 pixels -> softmax combine is a single __shfl_xor(32)).
// Spatial gaussian (sigma=0.1) is a delta => sp = q (off-center w < 2e-22).
// compat == -I (runtime-verified per block) => pairwise_i = -m_i.
// ---------------------------------------------------------------------------
__global__ __launch_bounds__(512, 4) void crf_iter_kernel(
        const float* __restrict__ qin, const float* __restrict__ w,
        const float* __restrict__ logits, const float* __restrict__ compat,
        float* __restrict__ qout) {
    __shared__ float sq[C][LH][LW];     // 36288 B
    __shared__ float scm[C * C];        // 1764 B
    __shared__ float sm[TW * TH][C];    // 21504 B (slow path only)

    int b = blockIdx.z;
    int x0 = blockIdx.x * TW, y0 = blockIdx.y * TH;
    int tid = threadIdx.x;
    int px = tid & 31;
    int half = (tid >> 5) & 1;
    int py = tid >> 6;
    int x = x0 + px, y = y0 + py, p = y * W + x;
    int pi = py * TW + px;
    int cbase = half ? CA : 0;
    int nch = half ? (C - CA) : CA;

    // ---- issue per-pixel global loads early (hide under LDS staging) ----
    float wk[K2];
#pragma unroll
    for (int k = 0; k < K2; ++k) wk[k] = w[((size_t)b * K2 + k) * HW + p];
    const float* lgp = logits + (size_t)b * C * HW + p;
    float lgv[CA];
#pragma unroll
    for (int cc = 0; cc < CA; ++cc)
        lgv[cc] = (cc < nch) ? lgp[(size_t)(cbase + cc) * HW] : 0.f;

    // ---- stage compat (+ verify it is exactly -I) ----
    int ok = 1;
    for (int i = tid; i < C * C; i += 512) {
        float v = compat[i];
        scm[i] = v;
        float expv = (i / C == i % C) ? -1.0f : 0.0f;
        ok &= (v == expv);
    }
    // ---- stage q tile with 2-halo ----
    const float* qb = qin + (size_t)b * C * HW;
    for (int i = tid; i < C * LH * LW; i += 512) {
        int c = i / (LH * LW), r = i % (LH * LW);
        int ly = r / LW, lx = r % LW;
        int gy = y0 + ly - 2, gx = x0 + lx - 2;
        float v = 0.f;
        if ((unsigned)gy < H && (unsigned)gx < W)
            v = qb[(size_t)c * HW + gy * W + gx];
        sq[c][ly][lx] = v;
    }
    int fast = __syncthreads_and(ok);   // barrier + block-uniform -I flag

    // ---- bilateral message passing (own channels only) ----
    float m[CA];
#pragma unroll
    for (int cc = 0; cc < CA; ++cc) {
        m[cc] = 0.f;
        if (cc < nch) {
            int c = cbase + cc;
            float acc = sq[c][py + 2][px + 2];   // spatial (delta) term
#pragma unroll
            for (int k = 0; k < K2; ++k)
                acc += wk[k] * sq[c][py + k / K][px + k % K];
            m[cc] = acc;
        }
    }

    // ---- compatibility transform ----
    float z[CA];
    if (fast) {                          // compat == -I: z = logits + m
#pragma unroll
        for (int cc = 0; cc < CA; ++cc) z[cc] = lgv[cc] + m[cc];
    } else {                             // general matvec via LDS exchange
#pragma unroll
        for (int cc = 0; cc < CA; ++cc)
            if (cc < nch) sm[pi][cbase + cc] = m[cc];
        __syncthreads();
        float mall[C];
#pragma unroll
        for (int j = 0; j < C; ++j) mall[j] = sm[pi][j];
#pragma unroll
        for (int cc = 0; cc < CA; ++cc) {
            float pw = 0.f; int i0 = cbase + cc;
#pragma unroll
            for (int j = 0; j < C; ++j) pw += scm[i0 * C + j] * mall[j];
            z[cc] = lgv[cc] - pw;
        }
    }

    // ---- softmax across the two channel-halves (lanes l <-> l+32) ----
    float mx = -1e30f;
#pragma unroll
    for (int cc = 0; cc < CA; ++cc) if (cc < nch) mx = fmaxf(mx, z[cc]);
    mx = fmaxf(mx, __shfl_xor(mx, 32));
    float s = 0.f;
#pragma unroll
    for (int cc = 0; cc < CA; ++cc)
        if (cc < nch) { z[cc] = __expf(z[cc] - mx); s += z[cc]; }
    s += __shfl_xor(s, 32);
    float inv = 1.f / s;
    float* qo = qout + (size_t)b * C * HW + p;
#pragma unroll
    for (int cc = 0; cc < CA; ++cc)
        if (cc < nch) qo[(size_t)(cbase + cc) * HW] = z[cc] * inv;
}

// ---------------------------------------------------------------------------
extern "C" void kernel_launch(void* const* d_in, const int* in_sizes, int n_in,
                              void* d_out, int out_size, void* d_ws, size_t ws_size,
                              hipStream_t stream) {
    const float* logits = (const float*)d_in[0];
    const float* img    = (const float*)d_in[1];
    // d_in[2] = gt_edges (dead code in reference)
    const float* compat = (const float*)d_in[3];
    float* out = (float*)d_out;

    char* ws = (char*)d_ws;
    float* w  = (float*)ws;                                   // Bn*K2*HW floats
    float* qa = (float*)(ws + (size_t)Bn * K2 * HW * 4);      // Bn*C*HW floats
    float* qb = qa + (size_t)Bn * C * HW;

    int npix = Bn * HW;
    int nb = (npix + 255) / 256;
    prep_kernel<<<nb, 256, 0, stream>>>(img, logits, w, qa);

    dim3 grid(W / TW, H / TH, Bn);
    crf_iter_kernel<<<grid, 512, 0, stream>>>(qa, w, logits, compat, qb);
    crf_iter_kernel<<<grid, 512, 0, stream>>>(qb, w, logits, compat, qa);
    crf_iter_kernel<<<grid, 512, 0, stream>>>(qa, w, logits, compat, qb);
    crf_iter_kernel<<<grid, 512, 0, stream>>>(qb, w, logits, compat, qa);
    crf_iter_kernel<<<grid, 512, 0, stream>>>(qa, w, logits, compat, out);
}